// Round 1
// baseline (1322.755 us; speedup 1.0000x reference)
//
#include <hip/hip_runtime.h>

// ---------------------------------------------------------------------------
// Decoder (GRU, T=50 steps) on MI355X.
// Round 0: correctness-first structured baseline.
//   - All GEMMs are A[M,K] @ W[N,K]^T -> one bf16 MFMA kernel, templated epilogue.
//   - ses-part of Hfull@Whh^T is step-invariant -> precomputed (ghc), so the
//     sequential per-step GEMM is only h(512) x Whh[:, :512]^T.
//   - gx (input gates) batched over all 50 steps; o/logits batched after scan.
//   - Big intermediates (gx_all, emb_bf, hnew_all) live in d_out scratch;
//     they are fully consumed before the logits GEMM rewrites d_out.
// Dims: V=10004 E=300 SH=1024 H=512 G=1024 B=128 T=50.
// ---------------------------------------------------------------------------

typedef __bf16 bf16x8 __attribute__((ext_vector_type(8)));
typedef float f32x4 __attribute__((ext_vector_type(4)));

// ---------------- fp32 -> bf16 (padded) conversion -------------------------
__global__ void cvt_kernel(const float* __restrict__ src, int srows, int scols,
                           int sstride, int soff,
                           __bf16* __restrict__ dst, int drows, int dcols) {
    int idx = blockIdx.x * 256 + threadIdx.x;
    int total = drows * dcols;
    if (idx >= total) return;
    int r = idx / dcols, c = idx % dcols;
    float v = 0.0f;
    if (r < srows && c < scols) v = src[(size_t)r * sstride + soff + c];
    dst[idx] = (__bf16)v;
}

// ---------------- embedding gather -> bf16 [t*128+b][320] ------------------
__global__ void emb_kernel(const int* __restrict__ x, const float* __restrict__ emb,
                           __bf16* __restrict__ embbf) {
    int m = blockIdx.x;            // m = t*128 + b
    int t = m >> 7, b = m & 127;
    int tok = x[b * 50 + t];
    const float* src = emb + (size_t)tok * 300;
    for (int i = threadIdx.x; i < 320; i += 64) {
        float v = (i < 300) ? src[i] : 0.0f;
        embbf[(size_t)m * 320 + i] = (__bf16)v;
    }
}

// ---------------- generic bf16 MFMA GEMM: C = A @ B^T ----------------------
// A: [M][lda] bf16 (M multiple of 128), B: [Brows][ldb] bf16 rows=output cols.
// Tile 128x128, BK=32, 4 waves, each wave a 64x64 quadrant (4x4 MFMA tiles).
struct GemmParams {
    const __bf16* A; int lda;
    const __bf16* B; int ldb; int Brows;
    int K;
    const float* bias;
    float* outF; int ldo; int Nstore;
    __bf16* outBf;
    const __bf16* res;     // EPI 2: residual (emb_bf), row-indexed like A
};

// EPI: 0 = f32 store (+optional bias)        (ghc, gx, gh)
//      1 = tanh, dual f32+bf16 store         (ses)
//      2 = bias + residual, bf16 store, row remap (t,b)->(b,t)   (o)
//      3 = plain f32 store with col guard    (logits)
template <int EPI>
__launch_bounds__(256, 2)
__global__ void gemm_bt(GemmParams p) {
    __shared__ __bf16 As[128][40];   // 32 data + 8 pad -> 80B rows (16B aligned)
    __shared__ __bf16 Bs[128][40];

    const int tid = threadIdx.x;
    const int lane = tid & 63;
    const int wid = tid >> 6;
    const int wr = wid >> 1, wc = wid & 1;
    const int m0 = blockIdx.x * 128, c0 = blockIdx.y * 128;
    const int lrow = lane & 15;
    const int kq = lane >> 4;        // 0..3

    f32x4 acc[4][4];
#pragma unroll
    for (int i = 0; i < 4; ++i)
#pragma unroll
        for (int j = 0; j < 4; ++j) acc[i][j] = (f32x4){0.f, 0.f, 0.f, 0.f};

    for (int kb = 0; kb < p.K; kb += 32) {
        // ---- stage A,B tiles (bf16 global -> LDS), 512 16B chunks each half
#pragma unroll
        for (int i = 0; i < 2; ++i) {
            int chunk = i * 256 + tid;        // 0..511
            int row = chunk >> 2;
            int cc = (chunk & 3) * 8;
            bf16x8 va = *reinterpret_cast<const bf16x8*>(
                p.A + (size_t)(m0 + row) * p.lda + kb + cc);
            *reinterpret_cast<bf16x8*>(&As[row][cc]) = va;
            bf16x8 vb;
#pragma unroll
            for (int q = 0; q < 8; ++q) vb[q] = (__bf16)0.0f;
            int grow = c0 + row;
            if (grow < p.Brows)
                vb = *reinterpret_cast<const bf16x8*>(
                    p.B + (size_t)grow * p.ldb + kb + cc);
            *reinterpret_cast<bf16x8*>(&Bs[row][cc]) = vb;
        }
        __syncthreads();

        bf16x8 af[4], bfr[4];
#pragma unroll
        for (int m = 0; m < 4; ++m)
            af[m] = *reinterpret_cast<const bf16x8*>(&As[wr * 64 + m * 16 + lrow][kq * 8]);
#pragma unroll
        for (int n = 0; n < 4; ++n)
            bfr[n] = *reinterpret_cast<const bf16x8*>(&Bs[wc * 64 + n * 16 + lrow][kq * 8]);
#pragma unroll
        for (int m = 0; m < 4; ++m)
#pragma unroll
            for (int n = 0; n < 4; ++n)
                acc[m][n] = __builtin_amdgcn_mfma_f32_16x16x32_bf16(
                    af[m], bfr[n], acc[m][n], 0, 0, 0);
        __syncthreads();
    }

    // ---- epilogue.  D layout: col = lane&15, row = (lane>>4)*4 + i
#pragma unroll
    for (int m = 0; m < 4; ++m) {
#pragma unroll
        for (int n = 0; n < 4; ++n) {
#pragma unroll
            for (int i = 0; i < 4; ++i) {
                int r = m0 + wr * 64 + m * 16 + kq * 4 + i;
                int c = c0 + wc * 64 + n * 16 + lrow;
                float v = acc[m][n][i];
                if constexpr (EPI == 0) {
                    if (c < p.Nstore) {
                        if (p.bias) v += p.bias[c];
                        p.outF[(size_t)r * p.ldo + c] = v;
                    }
                } else if constexpr (EPI == 1) {
                    v = tanhf(v + p.bias[c]);
                    p.outF[(size_t)r * p.ldo + c] = v;
                    p.outBf[(size_t)r * p.ldo + c] = (__bf16)v;
                } else if constexpr (EPI == 2) {
                    // r = t*128+b  ->  output row b*50+t ; bf16 store, pad cols zeroed
                    int ro = (r & 127) * 50 + (r >> 7);
                    if (c < 300) {
                        v += p.bias[c] + (float)p.res[(size_t)r * 320 + c];
                        p.outBf[(size_t)ro * 320 + c] = (__bf16)v;
                    } else if (c < 320) {
                        p.outBf[(size_t)ro * 320 + c] = (__bf16)0.0f;
                    }
                } else {  // EPI == 3
                    if (c < p.Nstore) p.outF[(size_t)r * p.ldo + c] = v;
                }
            }
        }
    }
}

// ---------------- GRU gate fusion (per step) -------------------------------
// gh = h @ Whh_a^T (raw); ghc = ses @ Whh_b^T + bhh; gx includes bih.
__global__ void gates_kernel(const float* __restrict__ gh, const float* __restrict__ ghc,
                             const float* __restrict__ gx, const float* __restrict__ hprev,
                             const float* __restrict__ ses,
                             float* __restrict__ hnext, __bf16* __restrict__ hnext_bf,
                             __bf16* __restrict__ hall) {
    int b = blockIdx.x;
    int base = b * 3072;
#pragma unroll
    for (int it = 0; it < 4; ++it) {
        int j = it * 256 + threadIdx.x;            // 0..1023
        float gr = gx[base + j] + gh[base + j] + ghc[base + j];
        float gz = gx[base + 1024 + j] + gh[base + 1024 + j] + ghc[base + 1024 + j];
        float ghn = gh[base + 2048 + j] + ghc[base + 2048 + j];
        float gxn = gx[base + 2048 + j];
        float r = 1.0f / (1.0f + expf(-gr));
        float z = 1.0f / (1.0f + expf(-gz));
        float n = tanhf(gxn + r * ghn);
        float hf = (j < 512) ? hprev[b * 512 + j] : ses[b * 512 + (j - 512)];
        float hn = (1.0f - z) * n + z * hf;
        hall[(size_t)b * 1024 + j] = (__bf16)hn;
        if (j < 512) {
            hnext[b * 512 + j] = hn;
            hnext_bf[b * 512 + j] = (__bf16)hn;
        }
    }
}

// ---------------------------------------------------------------------------
extern "C" void kernel_launch(void* const* d_in, const int* in_sizes, int n_in,
                              void* d_out, int out_size, void* d_ws, size_t ws_size,
                              hipStream_t stream) {
    const float* ses_enc = (const float*)d_in[0];
    const int*   x       = (const int*)d_in[1];
    const float* emb     = (const float*)d_in[2];
    const float* Wih     = (const float*)d_in[3];
    const float* Whh     = (const float*)d_in[4];
    const float* bih     = (const float*)d_in[5];
    const float* bhh     = (const float*)d_in[6];
    const float* W1      = (const float*)d_in[7];
    const float* b1      = (const float*)d_in[8];
    const float* W2      = (const float*)d_in[9];
    const float* b2      = (const float*)d_in[10];
    const float* Wout    = (const float*)d_in[11];
    float* out = (float*)d_out;

    // ---- workspace layout (bytes) ----
    char* ws = (char*)d_ws;
    float*  ses_f32   = (float*)(ws + 0);          // 128*512*4
    __bf16* ses_bf    = (__bf16*)(ws + 262144);    // 128*512*2
    float*  ghc       = (float*)(ws + 393216);     // 128*3072*4
    float*  gh_buf    = (float*)(ws + 1966080);    // 128*3072*4
    float*  hbufs[2]  = {(float*)(ws + 3538944), (float*)(ws + 3801088)};
    __bf16* hbfs[2]   = {(__bf16*)(ws + 4063232), (__bf16*)(ws + 4194304)};
    __bf16* o_bf      = (__bf16*)(ws + 4325376);   // 6400*320*2
    __bf16* W1_bf     = (__bf16*)(ws + 8421376);   // 512*1024*2
    __bf16* Whh_a_bf  = (__bf16*)(ws + 9469952);   // 3072*512*2
    __bf16* Whh_b_bf  = (__bf16*)(ws + 12615680);  // 3072*512*2
    __bf16* Wih_bf    = (__bf16*)(ws + 15761408);  // 3072*320*2
    __bf16* W2_bf     = (__bf16*)(ws + 17727488);  // 300*1024*2
    __bf16* Wout_bf   = (__bf16*)(ws + 18341888);  // 10112*320*2
    __bf16* sesenc_bf = (__bf16*)(ws + 24813568);  // 128*1024*2
    // total ws use ~25.1 MB

    // ---- d_out used as scratch for intermediates consumed before logits ----
    char* ob = (char*)d_out;
    float*  gx_all  = (float*)ob;                  // 50*128*3072*4 = 78,643,200
    __bf16* emb_bf  = (__bf16*)(ob + 80000000);    // 6400*320*2    =  4,096,000
    __bf16* hall_bf = (__bf16*)(ob + 88000000);    // 6400*1024*2   = 13,107,200

    dim3 blk(256);
    auto cvt = [&](const float* src, int sr, int sc, int ss, int so,
                   __bf16* dst, int dr, int dc) {
        int total = dr * dc;
        cvt_kernel<<<(total + 255) / 256, 256, 0, stream>>>(src, sr, sc, ss, so, dst, dr, dc);
    };
    cvt(W1,      512, 1024, 1024, 0,   W1_bf,     512, 1024);
    cvt(Whh,    3072,  512, 1024, 0,   Whh_a_bf, 3072,  512);
    cvt(Whh,    3072,  512, 1024, 512, Whh_b_bf, 3072,  512);
    cvt(Wih,    3072,  300,  300, 0,   Wih_bf,   3072,  320);
    cvt(W2,      300, 1024, 1024, 0,   W2_bf,     300, 1024);
    cvt(Wout,  10004,  300,  300, 0,   Wout_bf, 10112,  320);
    cvt(ses_enc, 128, 1024, 1024, 0,   sesenc_bf, 128, 1024);
    emb_kernel<<<6400, 64, 0, stream>>>(x, emb, emb_bf);

    GemmParams P;

    // ses = tanh(ses_enc @ W1^T + b1)  -> f32 + bf16
    P = {sesenc_bf, 1024, W1_bf, 1024, 512, 1024, b1, ses_f32, 512, 512, ses_bf, nullptr};
    gemm_bt<1><<<dim3(1, 4), blk, 0, stream>>>(P);

    // ghc = ses @ Whh[:,512:]^T + bhh   (step-invariant hidden contribution)
    P = {ses_bf, 512, Whh_b_bf, 512, 3072, 512, bhh, ghc, 3072, 3072, nullptr, nullptr};
    gemm_bt<0><<<dim3(1, 24), blk, 0, stream>>>(P);

    // gx_all[t][b] = emb @ Wih^T + bih   (all steps batched)
    P = {emb_bf, 320, Wih_bf, 320, 3072, 320, bih, gx_all, 3072, 3072, nullptr, nullptr};
    gemm_bt<0><<<dim3(50, 24), blk, 0, stream>>>(P);

    // ---- sequential scan ----
    for (int t = 0; t < 50; ++t) {
        const __bf16* hA = (t == 0) ? ses_bf  : hbfs[t & 1];
        const float*  hF = (t == 0) ? ses_f32 : hbufs[t & 1];
        P = {hA, 512, Whh_a_bf, 512, 3072, 512, nullptr, gh_buf, 3072, 3072, nullptr, nullptr};
        gemm_bt<0><<<dim3(1, 24), blk, 0, stream>>>(P);
        gates_kernel<<<128, 256, 0, stream>>>(
            gh_buf, ghc, gx_all + (size_t)t * 128 * 3072, hF, ses_f32,
            hbufs[(t + 1) & 1], hbfs[(t + 1) & 1], hall_bf + (size_t)t * 128 * 1024);
    }

    // o = hnew @ W2^T + b2 + emb   -> bf16, rows remapped (t,b) -> (b,t)
    P = {hall_bf, 1024, W2_bf, 1024, 300, 1024, b2, nullptr, 0, 300, o_bf, emb_bf};
    gemm_bt<2><<<dim3(50, 3), blk, 0, stream>>>(P);

    // logits = o @ Wout^T  -> d_out f32 (overwrites all scratch regions)
    P = {o_bf, 320, Wout_bf, 320, 10112, 320, nullptr, out, 10004, 10004, nullptr, nullptr};
    gemm_bt<3><<<dim3(50, 79), blk, 0, stream>>>(P);

    (void)in_sizes; (void)n_in; (void)out_size; (void)ws_size;
}